// Round 10
// baseline (1799.746 us; speedup 1.0000x reference)
//
#include <hip/hip_runtime.h>
#include <hip/hip_bf16.h>

#define TPB 256
#define TSTEPS 512
#define NROWS 8   // batch rows per block (A rows 8..15 are zero-pad -> 2 blocks/CU)

typedef __attribute__((ext_vector_type(8))) short bfrag;   // 8 bf16 (4 VGPRs)
typedef __attribute__((ext_vector_type(4))) float f32x4;   // MFMA C/D

#define LD4(p) (*reinterpret_cast<const float4*>(p))
#define MFMA(a, b, c) __builtin_amdgcn_mfma_f32_16x16x32_bf16((a), (b), (c), 0, 0, 0)

__device__ __forceinline__ float fast_rcp(float x) {
  float r; asm("v_rcp_f32 %0, %1" : "=v"(r) : "v"(x)); return r;
}
__device__ __forceinline__ float sigf(float x) { return fast_rcp(1.f + __expf(-x)); }
__device__ __forceinline__ float tanh_f(float x) {
  float y = fminf(fmaxf(x, -15.f), 15.f);
  float e = __expf(2.f * y);
  return (e - 1.f) * fast_rcp(e + 1.f);
}
__device__ __forceinline__ unsigned short f2bf(float f) {
  __hip_bfloat16 h = __float2bfloat16(f);
  return *reinterpret_cast<unsigned short*>(&h);
}
__device__ __forceinline__ float bf2f(unsigned short u) {
  __hip_bfloat16 h; *reinterpret_cast<unsigned short*>(&h) = u;
  return __bfloat162float(h);
}
// hot-path split: hi = truncate-to-bf16 (exact), lo = bf16(remainder); hi+lo == x to ~2^-17
__device__ __forceinline__ void split_tr(float x, unsigned short& hi, unsigned short& lo) {
  const unsigned u = __float_as_uint(x) & 0xffff0000u;
  hi = (unsigned short)(u >> 16);
  lo = f2bf(x - __uint_as_float(u));
}

// setup-path split (RNE)
#define SPLIT8(V, FH, FL) do { \
  _Pragma("unroll") \
  for (int j_ = 0; j_ < 8; ++j_) { \
    const unsigned short h_ = f2bf(V[j_]); \
    FH[j_] = (short)h_; \
    FL[j_] = (short)f2bf(V[j_] - bf2f(h_)); \
  } } while (0)

// HB: h as bf16 [buf][hl][row b][72 cells pad]
#define HBI(buf, hl, b) ((((buf)*2 + (hl))*16 + (b)) * 72)

__global__ void __launch_bounds__(TPB, 2) lstm_mfma(
    const float* __restrict__ X,    const float* __restrict__ eWih,
    const float* __restrict__ eWhh, const float* __restrict__ eb,
    const float* __restrict__ dWih, const float* __restrict__ dWhh,
    const float* __restrict__ db,   const float* __restrict__ hWp,
    const float* __restrict__ hbp,  float* __restrict__ out)
{
  __shared__ __align__(16) unsigned long long XF[4096];   // x A-frags b64-SoA: [t][dp][hl][lane]
  __shared__ __align__(16) unsigned short HB[2*2*16*72];  // h bf16 double-buffered
  __shared__ __align__(16) float HWs[16*72];              // head W fp32 (for decoder fold)
  __shared__ float HBS[16];                               // head bias

  const int tid = threadIdx.x;
  const int w = tid >> 6, l = tid & 63;        // wave w = cellblock; lane l
  const int c = l & 15, q = l >> 4;            // A-row / D-col index, k-quadrant
  const int bb0 = blockIdx.x * NROWS;

  // ---- init: zero XF (zero-pads k>=16 and rows>=NROWS forever) + HB; stage head W ----
  for (int i = tid; i < 4096; i += TPB) XF[i] = 0ULL;
  for (int i = tid; i < 2*2*16*72; i += TPB) HB[i] = 0;
  {
    const int o = tid >> 4, k4 = tid & 15;
    *reinterpret_cast<float4*>(&HWs[o*72 + k4*4]) = LD4(hWp + o*64 + k4*4);
    if (tid < 16) HBS[tid] = hbp[tid];
  }

  // ---- encoder weight fragments (B-operand, hi/lo split, in registers) ----
  bfrag wh_h[4][2], wh_l[4][2], wi_h[4], wi_l[4];
  float bias[4];
  #pragma unroll
  for (int G = 0; G < 4; ++G) {
    const int g = G*64 + w*16 + c;
    bias[G] = eb[g];
    #pragma unroll
    for (int kt = 0; kt < 2; ++kt) {
      float v[8];
      #pragma unroll
      for (int j = 0; j < 8; ++j) v[j] = eWhh[g*64 + kt*32 + q*8 + j];
      SPLIT8(v, wh_h[G][kt], wh_l[G][kt]);
    }
    {
      float v[8];
      #pragma unroll
      for (int j = 0; j < 8; ++j) { const int k = q*8 + j; v[j] = (k < 16) ? eWih[g*16 + k] : 0.f; }
      SPLIT8(v, wi_h[G], wi_l[G]);
    }
  }
  bfrag hwf_h[2], hwf_l[2];
  #pragma unroll
  for (int kt = 0; kt < 2; ++kt) {
    float v[8];
    #pragma unroll
    for (int j = 0; j < 8; ++j) v[j] = hWp[c*64 + kt*32 + q*8 + j];
    SPLIT8(v, hwf_h[kt], hwf_l[kt]);
  }
  const float hbv = hbp[c];

  float cc[4] = {0.f, 0.f, 0.f, 0.f};          // rows b=4q+r (only q<2 valid)

  // ================ encoder: 512 steps ================
  for (int t = 0; t < TSTEPS; ++t) {
    const int tt = t & 15;
    if (tt == 0) {
      __syncthreads();                         // old-chunk XF reads done
      #pragma unroll
      for (int r = 0; r < 2; ++r) {            // NROWS*16*4/TPB = 2 reps
        const int fidx = r * TPB + tid;
        const int i4 = fidx & 3, ts = (fidx >> 2) & 15, b = fidx >> 6;  // b 0..7
        const float4 v = LD4(X + ((size_t)(bb0 + b) * TSTEPS + (t + ts)) * 16 + i4 * 4);
        unsigned short hx, lx, hy, ly, hz, lz, hw2, lw;
        split_tr(v.x, hx, lx); split_tr(v.y, hy, ly);
        split_tr(v.z, hz, lz); split_tr(v.w, hw2, lw);
        const int dp = i4 & 1, slot = (i4 >> 1) * 16 + b;
        XF[((ts*2 + dp)*2 + 0)*64 + slot] =
            (unsigned long long)((unsigned)hx | ((unsigned)hy << 16)) |
            ((unsigned long long)((unsigned)hz | ((unsigned)hw2 << 16)) << 32);
        XF[((ts*2 + dp)*2 + 1)*64 + slot] =
            (unsigned long long)((unsigned)lx | ((unsigned)ly << 16)) |
            ((unsigned long long)((unsigned)lz | ((unsigned)lw << 16)) << 32);
      }
    }
    __syncthreads();                           // h(t-1) + XF visible
    const int rb = t & 1;

    bfrag ah_h[2], ah_l[2], ax_h, ax_l;
    #pragma unroll
    for (int kt = 0; kt < 2; ++kt) {
      ah_h[kt] = *reinterpret_cast<const bfrag*>(&HB[HBI(rb, 0, c) + kt*32 + q*8]);
      ah_l[kt] = *reinterpret_cast<const bfrag*>(&HB[HBI(rb, 1, c) + kt*32 + q*8]);
    }
    {
      union { bfrag f; unsigned long long d2[2]; } uh, ul;
      uh.d2[0] = XF[((tt*2 + 0)*2 + 0)*64 + l]; uh.d2[1] = XF[((tt*2 + 1)*2 + 0)*64 + l];
      ul.d2[0] = XF[((tt*2 + 0)*2 + 1)*64 + l]; ul.d2[1] = XF[((tt*2 + 1)*2 + 1)*64 + l];
      ax_h = uh.f; ax_l = ul.f;
    }

    f32x4 acc[4];
    #pragma unroll
    for (int G = 0; G < 4; ++G) { f32x4 z = {bias[G], bias[G], bias[G], bias[G]}; acc[G] = z; }
    #pragma unroll
    for (int G = 0; G < 4; ++G) {
      acc[G] = MFMA(ax_h, wi_h[G], acc[G]);
      acc[G] = MFMA(ax_h, wi_l[G], acc[G]);
      acc[G] = MFMA(ax_l, wi_h[G], acc[G]);
      #pragma unroll
      for (int kt = 0; kt < 2; ++kt) {
        acc[G] = MFMA(ah_h[kt], wh_h[G][kt], acc[G]);
        acc[G] = MFMA(ah_h[kt], wh_l[G][kt], acc[G]);
        acc[G] = MFMA(ah_l[kt], wh_h[G][kt], acc[G]);
      }
    }

    const int wb = rb ^ 1;
    if (q < 2) {                               // rows b=4q+r < 8 only
      #pragma unroll
      for (int r = 0; r < 4; ++r) {
        const float ig = sigf(acc[0][r]), fg = sigf(acc[1][r]);
        const float gg = tanh_f(acc[2][r]), og = sigf(acc[3][r]);
        cc[r] = fg * cc[r] + ig * gg;
        const float h = og * tanh_f(cc[r]);
        unsigned short hh, hl2;
        split_tr(h, hh, hl2);
        const int b = q*4 + r;
        HB[HBI(wb, 0, b) + w*16 + c] = hh;
        HB[HBI(wb, 1, b) + w*16 + c] = hl2;
      }
    }
  }

  // ---- decoder raw weights (step 0: prev=0 -> gates = dWhh*h + db) ----
  #pragma unroll
  for (int G = 0; G < 4; ++G) {
    const int g = G*64 + w*16 + c;
    bias[G] = db[g];
    #pragma unroll
    for (int kt = 0; kt < 2; ++kt) {
      float v[8];
      #pragma unroll
      for (int j = 0; j < 8; ++j) v[j] = dWhh[g*64 + kt*32 + q*8 + j];
      SPLIT8(v, wh_h[G][kt], wh_l[G][kt]);
    }
  }

  // ================ decoder: 512 autoregressive steps ================
  for (int t = 0; t < TSTEPS; ++t) {
    __syncthreads();
    const int rb = t & 1;
    bfrag ah_h[2], ah_l[2];
    #pragma unroll
    for (int kt = 0; kt < 2; ++kt) {
      ah_h[kt] = *reinterpret_cast<const bfrag*>(&HB[HBI(rb, 0, c) + kt*32 + q*8]);
      ah_l[kt] = *reinterpret_cast<const bfrag*>(&HB[HBI(rb, 1, c) + kt*32 + q*8]);
    }
    if (w == 3 && t > 0) {                     // head: pred(t-1) from h(t-1)
      f32x4 hd = {hbv, hbv, hbv, hbv};
      #pragma unroll
      for (int kt = 0; kt < 2; ++kt) {
        hd = MFMA(ah_h[kt], hwf_h[kt], hd);
        hd = MFMA(ah_h[kt], hwf_l[kt], hd);
        hd = MFMA(ah_l[kt], hwf_h[kt], hd);
      }
      if (q < 2) {
        #pragma unroll
        for (int r = 0; r < 4; ++r)
          out[((size_t)(bb0 + q*4 + r) * TSTEPS + (t - 1)) * 16 + c] = hd[r];
      }
    }

    f32x4 acc[4];
    #pragma unroll
    for (int G = 0; G < 4; ++G) { f32x4 z = {bias[G], bias[G], bias[G], bias[G]}; acc[G] = z; }
    #pragma unroll
    for (int G = 0; G < 4; ++G) {
      #pragma unroll
      for (int kt = 0; kt < 2; ++kt) {
        acc[G] = MFMA(ah_h[kt], wh_h[G][kt], acc[G]);
        acc[G] = MFMA(ah_h[kt], wh_l[G][kt], acc[G]);
        acc[G] = MFMA(ah_l[kt], wh_h[G][kt], acc[G]);
      }
    }

    const int wb = rb ^ 1;
    if (q < 2) {
      #pragma unroll
      for (int r = 0; r < 4; ++r) {
        const float ig = sigf(acc[0][r]), fg = sigf(acc[1][r]);
        const float gg = tanh_f(acc[2][r]), og = sigf(acc[3][r]);
        cc[r] = fg * cc[r] + ig * gg;
        const float h = og * tanh_f(cc[r]);
        unsigned short hh, hl2;
        split_tr(h, hh, hl2);
        const int b = q*4 + r;
        HB[HBI(wb, 0, b) + w*16 + c] = hh;
        HB[HBI(wb, 1, b) + w*16 + c] = hl2;
      }
    }

    if (t == 0) {                              // fold feedback: W += dWih*hW, b += dWih*hb
      #pragma unroll
      for (int G = 0; G < 4; ++G) {
        const int g = G*64 + w*16 + c;
        float dwv[16];
        #pragma unroll
        for (int o4 = 0; o4 < 4; ++o4) {
          const float4 v = LD4(dWih + g*16 + o4*4);
          dwv[o4*4+0] = v.x; dwv[o4*4+1] = v.y; dwv[o4*4+2] = v.z; dwv[o4*4+3] = v.w;
        }
        float bb = db[g];
        #pragma unroll
        for (int o = 0; o < 16; ++o) bb += dwv[o] * HBS[o];
        bias[G] = bb;
        #pragma unroll
        for (int kt = 0; kt < 2; ++kt) {
          float v[8];
          #pragma unroll
          for (int j = 0; j < 8; ++j) {
            const int k = kt*32 + q*8 + j;
            float ww = dWhh[g*64 + k];
            #pragma unroll
            for (int o = 0; o < 16; ++o) ww += dwv[o] * HWs[o*72 + k];
            v[j] = ww;
          }
          SPLIT8(v, wh_h[G][kt], wh_l[G][kt]);
        }
      }
    }
  }

  // ---- epilogue: pred(511) from h(511) ----
  __syncthreads();
  if (w == 3) {
    const int rb = TSTEPS & 1;
    bfrag ah_h[2], ah_l[2];
    #pragma unroll
    for (int kt = 0; kt < 2; ++kt) {
      ah_h[kt] = *reinterpret_cast<const bfrag*>(&HB[HBI(rb, 0, c) + kt*32 + q*8]);
      ah_l[kt] = *reinterpret_cast<const bfrag*>(&HB[HBI(rb, 1, c) + kt*32 + q*8]);
    }
    f32x4 hd = {hbv, hbv, hbv, hbv};
    #pragma unroll
    for (int kt = 0; kt < 2; ++kt) {
      hd = MFMA(ah_h[kt], hwf_h[kt], hd);
      hd = MFMA(ah_h[kt], hwf_l[kt], hd);
      hd = MFMA(ah_l[kt], hwf_h[kt], hd);
    }
    if (q < 2) {
      #pragma unroll
      for (int r = 0; r < 4; ++r)
        out[((size_t)(bb0 + q*4 + r) * TSTEPS + (TSTEPS - 1)) * 16 + c] = hd[r];
    }
  }
}

extern "C" void kernel_launch(void* const* d_in, const int* in_sizes, int n_in,
                              void* d_out, int out_size, void* d_ws, size_t ws_size,
                              hipStream_t stream) {
  (void)in_sizes; (void)n_in; (void)d_ws; (void)ws_size; (void)out_size;
  const float* X    = (const float*)d_in[0];
  const float* eWih = (const float*)d_in[1];
  const float* eWhh = (const float*)d_in[2];
  const float* eb   = (const float*)d_in[3];
  const float* dWih = (const float*)d_in[4];
  const float* dWhh = (const float*)d_in[5];
  const float* db   = (const float*)d_in[6];
  const float* hW   = (const float*)d_in[7];
  const float* hb   = (const float*)d_in[8];
  float* out = (float*)d_out;

  lstm_mfma<<<dim3(4096 / NROWS), dim3(TPB), 0, stream>>>(
      X, eWih, eWhh, eb, dWih, dWhh, db, hW, hb, out);
}

// Round 11
// 995.668 us; speedup vs baseline: 1.8076x; 1.8076x over previous
//
#include <hip/hip_runtime.h>
#include <hip/hip_bf16.h>

#define TPB 512
#define TSTEPS 512
#define NROWS 16
#define CHUNK 8

typedef __attribute__((ext_vector_type(8))) short bfrag;   // 8 bf16 (4 VGPRs)
typedef __attribute__((ext_vector_type(4))) float f32x4;   // MFMA C/D

#define LD4(p) (*reinterpret_cast<const float4*>(p))
#define MFMA(a, b, c) __builtin_amdgcn_mfma_f32_16x16x32_bf16((a), (b), (c), 0, 0, 0)

__device__ __forceinline__ float fast_rcp(float x) {
  float r; asm("v_rcp_f32 %0, %1" : "=v"(r) : "v"(x)); return r;
}
__device__ __forceinline__ float sigf(float x) { return fast_rcp(1.f + __expf(-x)); }
__device__ __forceinline__ float tanh_f(float x) {
  float y = fminf(fmaxf(x, -15.f), 15.f);
  float e = __expf(2.f * y);
  return (e - 1.f) * fast_rcp(e + 1.f);
}
__device__ __forceinline__ unsigned short f2bf(float f) {
  __hip_bfloat16 h = __float2bfloat16(f);
  return *reinterpret_cast<unsigned short*>(&h);
}
__device__ __forceinline__ float bf2f(unsigned short u) {
  __hip_bfloat16 h; *reinterpret_cast<unsigned short*>(&h) = u;
  return __bfloat162float(h);
}
__device__ __forceinline__ void split_tr(float x, unsigned short& hi, unsigned short& lo) {
  const unsigned u = __float_as_uint(x) & 0xffff0000u;
  hi = (unsigned short)(u >> 16);
  lo = f2bf(x - __uint_as_float(u));
}

#define SPLIT8(V, FH, FL) do { \
  _Pragma("unroll") \
  for (int j_ = 0; j_ < 8; ++j_) { \
    const unsigned short h_ = f2bf(V[j_]); \
    FH[j_] = (short)h_; \
    FL[j_] = (short)f2bf(V[j_] - bf2f(h_)); \
  } } while (0)

// HB: h bf16 [buf][hl][row 16][72 cells pad]
#define HBI(buf, hl, b) ((((buf)*2 + (hl))*16 + (b)) * 72)

__global__ void __launch_bounds__(TPB, 2) lstm_mfma(
    const float* __restrict__ X,    const float* __restrict__ eWih,
    const float* __restrict__ eWhh, const float* __restrict__ eb,
    const float* __restrict__ dWih, const float* __restrict__ dWhh,
    const float* __restrict__ db,   const float* __restrict__ hWp,
    const float* __restrict__ hbp,  float* __restrict__ out)
{
  __shared__ __align__(16) unsigned long long XF[CHUNK*2*64*2]; // 16KB: [t][hl][lane][dp]
  __shared__ __align__(16) unsigned short HB[2*2*16*72];        // 9216B
  __shared__ __align__(16) float GT[8][32*20];                  // per-wave gates, col-major [col][20]
  __shared__ __align__(16) float HWs[16*72];                    // head W fp32 (decoder fold)
  __shared__ float HBS[16];

  const int tid = threadIdx.x;
  const int w = tid >> 6, l = tid & 63;   // 8 waves; wave w owns cells [8w, 8w+8)
  const int c = l & 15, q = l >> 4;       // MFMA lane coords (col / k-quadrant / row-quad)
  const int cl = l >> 3, p = l & 7;       // cell-update coords: cell-local, row-pair
  const int G = c & 3, cu = c >> 2;       // gate type, cell-sub within tile
  const int bb0 = blockIdx.x * NROWS;
  const int mycell = w * 8 + cl;
  const int gg0 = G * 64 + w * 8 + cu;        // gate row for tile 0 col c
  const int gg1 = G * 64 + w * 8 + 4 + cu;    // tile 1
  const int colbase = (cl >> 2) * 16 + (cl & 3) * 4;  // GT col of my cell's gate 0
  float* gw = &GT[w][0];

  // ---- init ----
  for (int i = tid; i < CHUNK*2*64*2; i += TPB) XF[i] = 0ULL;
  for (int i = tid; i < 2*2*16*72; i += TPB) HB[i] = 0;
  if (tid < 256) {
    const int o = tid >> 4, k4 = tid & 15;
    *reinterpret_cast<float4*>(&HWs[o*72 + k4*4]) = LD4(hWp + o*64 + k4*4);
    if (tid < 16) HBS[tid] = hbp[tid];
  }

  // ---- encoder weight fragments (remapped cols: all 4 gates of my 8 cells) ----
  bfrag wh_h[2][2], wh_l[2][2], wi_h[2], wi_l[2];
  float bias2[2];
  #pragma unroll
  for (int T = 0; T < 2; ++T) {
    const int gg = T ? gg1 : gg0;
    bias2[T] = eb[gg];
    #pragma unroll
    for (int kt = 0; kt < 2; ++kt) {
      float v[8];
      #pragma unroll
      for (int j = 0; j < 8; ++j) v[j] = eWhh[gg*64 + kt*32 + q*8 + j];
      SPLIT8(v, wh_h[T][kt], wh_l[T][kt]);
    }
    {
      float v[8];
      #pragma unroll
      for (int j = 0; j < 8; ++j) { const int k = q*8 + j; v[j] = (k < 16) ? eWih[gg*16 + k] : 0.f; }
      SPLIT8(v, wi_h[T], wi_l[T]);
    }
  }
  bfrag hwf_h[2], hwf_l[2];
  #pragma unroll
  for (int kt = 0; kt < 2; ++kt) {
    float v[8];
    #pragma unroll
    for (int j = 0; j < 8; ++j) v[j] = hWp[c*64 + kt*32 + q*8 + j];
    SPLIT8(v, hwf_h[kt], hwf_l[kt]);
  }
  const float hbv = hbp[c];

  float cc0 = 0.f, cc1 = 0.f;   // c-state: cell mycell, rows 2p, 2p+1

  // ================ encoder: 512 steps ================
  for (int t = 0; t < TSTEPS; ++t) {
    const int tt = t & (CHUNK - 1);
    if (tt == 0) {
      __syncthreads();                       // old-chunk XF reads done
      const int i4 = tid & 3, ts = (tid >> 2) & 7, b = tid >> 5;   // 512 float4s
      const float4 v = LD4(X + ((size_t)(bb0 + b) * TSTEPS + (t + ts)) * 16 + i4 * 4);
      unsigned short hx, lx, hy, ly, hz, lz, hw2, lw;
      split_tr(v.x, hx, lx); split_tr(v.y, hy, ly);
      split_tr(v.z, hz, lz); split_tr(v.w, hw2, lw);
      const int dp = i4 & 1, slot = (i4 >> 1) * 16 + b;
      XF[((ts*2 + 0)*64 + slot)*2 + dp] =
          (unsigned long long)((unsigned)hx | ((unsigned)hy << 16)) |
          ((unsigned long long)((unsigned)hz | ((unsigned)hw2 << 16)) << 32);
      XF[((ts*2 + 1)*64 + slot)*2 + dp] =
          (unsigned long long)((unsigned)lx | ((unsigned)ly << 16)) |
          ((unsigned long long)((unsigned)lz | ((unsigned)lw << 16)) << 32);
    }
    __syncthreads();                         // h(t-1) + XF visible
    const int rb = t & 1;

    bfrag ah_h[2], ah_l[2];
    #pragma unroll
    for (int kt = 0; kt < 2; ++kt) {
      ah_h[kt] = *reinterpret_cast<const bfrag*>(&HB[HBI(rb, 0, c) + kt*32 + q*8]);
      ah_l[kt] = *reinterpret_cast<const bfrag*>(&HB[HBI(rb, 1, c) + kt*32 + q*8]);
    }
    const bfrag ax_h = *reinterpret_cast<const bfrag*>(&XF[((tt*2 + 0)*64 + l)*2]);
    const bfrag ax_l = *reinterpret_cast<const bfrag*>(&XF[((tt*2 + 1)*64 + l)*2]);

    f32x4 acc[2];
    #pragma unroll
    for (int T = 0; T < 2; ++T) { f32x4 z = {bias2[T], bias2[T], bias2[T], bias2[T]}; acc[T] = z; }
    #pragma unroll
    for (int T = 0; T < 2; ++T) {
      acc[T] = MFMA(ax_h, wi_h[T], acc[T]);
      acc[T] = MFMA(ax_h, wi_l[T], acc[T]);
      acc[T] = MFMA(ax_l, wi_h[T], acc[T]);
      #pragma unroll
      for (int kt = 0; kt < 2; ++kt) {
        acc[T] = MFMA(ah_h[kt], wh_h[T][kt], acc[T]);
        acc[T] = MFMA(ah_h[kt], wh_l[T][kt], acc[T]);
        acc[T] = MFMA(ah_l[kt], wh_h[T][kt], acc[T]);
      }
    }

    // gates -> per-wave LDS (col-major), intra-wave reshuffle (no barrier needed)
    #pragma unroll
    for (int T = 0; T < 2; ++T)
      *reinterpret_cast<f32x4*>(&gw[(T*16 + c)*20 + 4*q]) = acc[T];

    const float2 gi = *reinterpret_cast<const float2*>(&gw[(colbase + 0)*20 + 2*p]);
    const float2 gf = *reinterpret_cast<const float2*>(&gw[(colbase + 1)*20 + 2*p]);
    const float2 gg = *reinterpret_cast<const float2*>(&gw[(colbase + 2)*20 + 2*p]);
    const float2 go = *reinterpret_cast<const float2*>(&gw[(colbase + 3)*20 + 2*p]);

    const int wb = rb ^ 1;
    {
      const float ig = sigf(gi.x), fg = sigf(gf.x), gt = tanh_f(gg.x), og = sigf(go.x);
      cc0 = fg * cc0 + ig * gt;
      const float h = og * tanh_f(cc0);
      unsigned short hh, hl2; split_tr(h, hh, hl2);
      HB[HBI(wb, 0, 2*p + 0) + mycell] = hh;
      HB[HBI(wb, 1, 2*p + 0) + mycell] = hl2;
    }
    {
      const float ig = sigf(gi.y), fg = sigf(gf.y), gt = tanh_f(gg.y), og = sigf(go.y);
      cc1 = fg * cc1 + ig * gt;
      const float h = og * tanh_f(cc1);
      unsigned short hh, hl2; split_tr(h, hh, hl2);
      HB[HBI(wb, 0, 2*p + 1) + mycell] = hh;
      HB[HBI(wb, 1, 2*p + 1) + mycell] = hl2;
    }
  }

  // ---- decoder raw weights (step 0: prev=0 -> gates = dWhh*h + db) ----
  #pragma unroll
  for (int T = 0; T < 2; ++T) {
    const int gg = T ? gg1 : gg0;
    bias2[T] = db[gg];
    #pragma unroll
    for (int kt = 0; kt < 2; ++kt) {
      float v[8];
      #pragma unroll
      for (int j = 0; j < 8; ++j) v[j] = dWhh[gg*64 + kt*32 + q*8 + j];
      SPLIT8(v, wh_h[T][kt], wh_l[T][kt]);
    }
  }

  // ================ decoder: 512 autoregressive steps ================
  for (int t = 0; t < TSTEPS; ++t) {
    __syncthreads();
    const int rb = t & 1;
    bfrag ah_h[2], ah_l[2];
    #pragma unroll
    for (int kt = 0; kt < 2; ++kt) {
      ah_h[kt] = *reinterpret_cast<const bfrag*>(&HB[HBI(rb, 0, c) + kt*32 + q*8]);
      ah_l[kt] = *reinterpret_cast<const bfrag*>(&HB[HBI(rb, 1, c) + kt*32 + q*8]);
    }
    if (t > 0 && w == ((t - 1) & 7)) {       // rotating head: pred(t-1) from h(t-1)
      f32x4 hd = {hbv, hbv, hbv, hbv};
      #pragma unroll
      for (int kt = 0; kt < 2; ++kt) {
        hd = MFMA(ah_h[kt], hwf_h[kt], hd);
        hd = MFMA(ah_h[kt], hwf_l[kt], hd);
        hd = MFMA(ah_l[kt], hwf_h[kt], hd);
      }
      #pragma unroll
      for (int r = 0; r < 4; ++r)
        out[((size_t)(bb0 + 4*q + r) * TSTEPS + (t - 1)) * 16 + c] = hd[r];
    }

    f32x4 acc[2];
    #pragma unroll
    for (int T = 0; T < 2; ++T) { f32x4 z = {bias2[T], bias2[T], bias2[T], bias2[T]}; acc[T] = z; }
    #pragma unroll
    for (int T = 0; T < 2; ++T) {
      #pragma unroll
      for (int kt = 0; kt < 2; ++kt) {
        acc[T] = MFMA(ah_h[kt], wh_h[T][kt], acc[T]);
        acc[T] = MFMA(ah_h[kt], wh_l[T][kt], acc[T]);
        acc[T] = MFMA(ah_l[kt], wh_h[T][kt], acc[T]);
      }
    }

    #pragma unroll
    for (int T = 0; T < 2; ++T)
      *reinterpret_cast<f32x4*>(&gw[(T*16 + c)*20 + 4*q]) = acc[T];

    const float2 gi = *reinterpret_cast<const float2*>(&gw[(colbase + 0)*20 + 2*p]);
    const float2 gf = *reinterpret_cast<const float2*>(&gw[(colbase + 1)*20 + 2*p]);
    const float2 gg = *reinterpret_cast<const float2*>(&gw[(colbase + 2)*20 + 2*p]);
    const float2 go = *reinterpret_cast<const float2*>(&gw[(colbase + 3)*20 + 2*p]);

    const int wb = rb ^ 1;
    {
      const float ig = sigf(gi.x), fg = sigf(gf.x), gt = tanh_f(gg.x), og = sigf(go.x);
      cc0 = fg * cc0 + ig * gt;
      const float h = og * tanh_f(cc0);
      unsigned short hh, hl2; split_tr(h, hh, hl2);
      HB[HBI(wb, 0, 2*p + 0) + mycell] = hh;
      HB[HBI(wb, 1, 2*p + 0) + mycell] = hl2;
    }
    {
      const float ig = sigf(gi.y), fg = sigf(gf.y), gt = tanh_f(gg.y), og = sigf(go.y);
      cc1 = fg * cc1 + ig * gt;
      const float h = og * tanh_f(cc1);
      unsigned short hh, hl2; split_tr(h, hh, hl2);
      HB[HBI(wb, 0, 2*p + 1) + mycell] = hh;
      HB[HBI(wb, 1, 2*p + 1) + mycell] = hl2;
    }

    if (t == 0) {                            // fold feedback: W += dWih*hW, b += dWih*hb
      #pragma unroll
      for (int T = 0; T < 2; ++T) {
        const int gg2 = T ? gg1 : gg0;
        float dwv[16];
        #pragma unroll
        for (int o4 = 0; o4 < 4; ++o4) {
          const float4 v = LD4(dWih + gg2*16 + o4*4);
          dwv[o4*4+0] = v.x; dwv[o4*4+1] = v.y; dwv[o4*4+2] = v.z; dwv[o4*4+3] = v.w;
        }
        float bb = db[gg2];
        #pragma unroll
        for (int o = 0; o < 16; ++o) bb += dwv[o] * HBS[o];
        bias2[T] = bb;
        #pragma unroll
        for (int kt = 0; kt < 2; ++kt) {
          float v[8];
          #pragma unroll
          for (int j = 0; j < 8; ++j) {
            const int k = kt*32 + q*8 + j;
            float ww = dWhh[gg2*64 + k];
            #pragma unroll
            for (int o = 0; o < 16; ++o) ww += dwv[o] * HWs[o*72 + k];
            v[j] = ww;
          }
          SPLIT8(v, wh_h[T][kt], wh_l[T][kt]);
        }
      }
    }
  }

  // ---- epilogue: pred(511) from h(511) (in buf 0) ----
  __syncthreads();
  if (w == 7) {
    bfrag ah_h[2], ah_l[2];
    #pragma unroll
    for (int kt = 0; kt < 2; ++kt) {
      ah_h[kt] = *reinterpret_cast<const bfrag*>(&HB[HBI(0, 0, c) + kt*32 + q*8]);
      ah_l[kt] = *reinterpret_cast<const bfrag*>(&HB[HBI(0, 1, c) + kt*32 + q*8]);
    }
    f32x4 hd = {hbv, hbv, hbv, hbv};
    #pragma unroll
    for (int kt = 0; kt < 2; ++kt) {
      hd = MFMA(ah_h[kt], hwf_h[kt], hd);
      hd = MFMA(ah_h[kt], hwf_l[kt], hd);
      hd = MFMA(ah_l[kt], hwf_h[kt], hd);
    }
    #pragma unroll
    for (int r = 0; r < 4; ++r)
      out[((size_t)(bb0 + 4*q + r) * TSTEPS + (TSTEPS - 1)) * 16 + c] = hd[r];
  }
}

extern "C" void kernel_launch(void* const* d_in, const int* in_sizes, int n_in,
                              void* d_out, int out_size, void* d_ws, size_t ws_size,
                              hipStream_t stream) {
  (void)in_sizes; (void)n_in; (void)d_ws; (void)ws_size; (void)out_size;
  const float* X    = (const float*)d_in[0];
  const float* eWih = (const float*)d_in[1];
  const float* eWhh = (const float*)d_in[2];
  const float* eb   = (const float*)d_in[3];
  const float* dWih = (const float*)d_in[4];
  const float* dWhh = (const float*)d_in[5];
  const float* db   = (const float*)d_in[6];
  const float* hW   = (const float*)d_in[7];
  const float* hb   = (const float*)d_in[8];
  float* out = (float*)d_out;

  lstm_mfma<<<dim3(4096 / NROWS), dim3(TPB), 0, stream>>>(
      X, eWih, eWhh, eb, dWih, dWhh, db, hW, hb, out);
}